// Round 1
// baseline (7522.953 us; speedup 1.0000x reference)
//
#include <hip/hip_runtime.h>
#include <math.h>

#define B_ 4
#define J_ 6890
#define D_ 256
#define L_ 4
#define H_ 8
#define DH_ 64
#define INNER_ 512
#define N_ 2048
#define FF_ 1024
#define M_ 13780

typedef float4 f4;

__device__ __forceinline__ float gelu_f(float v) {
    return 0.5f * v * (1.0f + erff(v * 0.70710678118654752440f));
}

// ---------------------------------------------------------------------------
// Fused token-embed + 1x1 conv (J->N) + pos-emb + pre-LN.
// Algebraic fusion: out[b,n,d] = t0*W[0,d]+t1*W[1,d]+t2*W[2,d] + s*emb_b[d]
//                   + conv_b[n] + pos_emb[n,d],  t_p = sum_j conv_w[n,j]*x[b,j,p]
// ---------------------------------------------------------------------------
__global__ __launch_bounds__(256) void embed_ln_kernel(
    const float* __restrict__ x, const float* __restrict__ emb_w,
    const float* __restrict__ emb_b, const float* __restrict__ conv_w,
    const float* __restrict__ conv_b, const float* __restrict__ pos_emb,
    const float* __restrict__ g, const float* __restrict__ beta,
    float* __restrict__ hout)
{
    const int n = blockIdx.x, b = blockIdx.y, t = threadIdx.x;
    const float* wrow = conv_w + (size_t)n * J_;
    const float* xb = x + (size_t)b * J_ * 3;
    float t0 = 0.f, t1 = 0.f, t2 = 0.f, s = 0.f;
    for (int j = t; j < J_; j += 256) {
        float w = wrow[j];
        s  += w;
        t0 += w * xb[3*j+0];
        t1 += w * xb[3*j+1];
        t2 += w * xb[3*j+2];
    }
    __shared__ float red[16];
    #pragma unroll
    for (int off = 32; off > 0; off >>= 1) {
        t0 += __shfl_down(t0, off, 64);
        t1 += __shfl_down(t1, off, 64);
        t2 += __shfl_down(t2, off, 64);
        s  += __shfl_down(s,  off, 64);
    }
    const int lane = t & 63, wid = t >> 6;
    if (lane == 0) { red[wid*4+0]=t0; red[wid*4+1]=t1; red[wid*4+2]=t2; red[wid*4+3]=s; }
    __syncthreads();
    t0 = red[0]+red[4]+red[8]+red[12];
    t1 = red[1]+red[5]+red[9]+red[13];
    t2 = red[2]+red[6]+red[10]+red[14];
    s  = red[3]+red[7]+red[11]+red[15];
    __syncthreads();

    float val = t0*emb_w[t] + t1*emb_w[D_+t] + t2*emb_w[2*D_+t]
              + s*emb_b[t] + conv_b[n] + pos_emb[(size_t)n*D_ + t];

    // LayerNorm over the 256 block threads
    float sv = val, sq = val*val;
    #pragma unroll
    for (int off = 32; off > 0; off >>= 1) {
        sv += __shfl_down(sv, off, 64);
        sq += __shfl_down(sq, off, 64);
    }
    if (lane == 0) { red[wid*2]=sv; red[wid*2+1]=sq; }
    __syncthreads();
    sv = red[0]+red[2]+red[4]+red[6];
    sq = red[1]+red[3]+red[5]+red[7];
    float mu   = sv * (1.f/D_);
    float var  = sq * (1.f/D_) - mu*mu;
    float rstd = rsqrtf(fmaxf(var, 0.f) + 1e-5f);
    hout[((size_t)(b*N_ + n))*D_ + t] = (val - mu)*rstd*g[t] + beta[t];
}

// ---------------------------------------------------------------------------
// Row LayerNorm (rows of 256), one block per row
// ---------------------------------------------------------------------------
__global__ __launch_bounds__(256) void ln_kernel(
    const float* __restrict__ in, float* __restrict__ outp,
    const float* __restrict__ g, const float* __restrict__ beta)
{
    const int row = blockIdx.x, t = threadIdx.x;
    float v = in[(size_t)row*D_ + t];
    float sv = v, sq = v*v;
    #pragma unroll
    for (int off = 32; off > 0; off >>= 1) {
        sv += __shfl_down(sv, off, 64);
        sq += __shfl_down(sq, off, 64);
    }
    __shared__ float red[8];
    const int lane = t & 63, wid = t >> 6;
    if (lane == 0) { red[wid*2]=sv; red[wid*2+1]=sq; }
    __syncthreads();
    sv = red[0]+red[2]+red[4]+red[6];
    sq = red[1]+red[3]+red[5]+red[7];
    float mu   = sv * (1.f/D_);
    float var  = sq * (1.f/D_) - mu*mu;
    float rstd = rsqrtf(fmaxf(var, 0.f) + 1e-5f);
    outp[(size_t)row*D_ + t] = (v - mu)*rstd*g[t] + beta[t];
}

// ---------------------------------------------------------------------------
// Tiled SGEMM: C[M,N] (+= / =) A[M,K] @ B[K,N], 64x64 tile, 4x4 micro-tile.
// Epilogues: per-col bias, per-row bias, exact GELU, residual add.
// K % 16 == 0 and N % 64 == 0 always hold here; only M needs guarding.
// ---------------------------------------------------------------------------
template<int BIAS_COL, int BIAS_ROW, int GELU, int RESID>
__global__ __launch_bounds__(256) void sgemm_kernel(
    const float* __restrict__ A, int lda, long sA,
    const float* __restrict__ Bm, int ldb, long sB,
    float* __restrict__ C, int ldc, long sC,
    const float* __restrict__ bias,
    int M, int N, int K)
{
    const int bz = blockIdx.z;
    A  += (size_t)bz * sA;
    Bm += (size_t)bz * sB;
    C  += (size_t)bz * sC;
    const int m0 = blockIdx.y * 64, n0 = blockIdx.x * 64;
    const int t = threadIdx.x;
    const int tx = t & 15, ty = t >> 4;

    __shared__ float As[16][68];   // transposed A tile: As[k][m], pad 68 keeps f4 align
    __shared__ float Bs[16][68];   // Bs[k][n]

    float acc[4][4] = {};
    const int arow = t >> 2, ak = (t & 3) * 4;   // A loads: f4 along K
    const int bcol = t & 63, br0 = t >> 6;       // B loads: coalesced along N

    for (int k0 = 0; k0 < K; k0 += 16) {
        f4 a4 = make_float4(0.f, 0.f, 0.f, 0.f);
        if (m0 + arow < M)
            a4 = *(const f4*)&A[(size_t)(m0 + arow)*lda + k0 + ak];
        As[ak+0][arow] = a4.x;
        As[ak+1][arow] = a4.y;
        As[ak+2][arow] = a4.z;
        As[ak+3][arow] = a4.w;
        #pragma unroll
        for (int p = 0; p < 4; p++)
            Bs[br0 + p*4][bcol] = Bm[(size_t)(k0 + br0 + p*4)*ldb + n0 + bcol];
        __syncthreads();

        #pragma unroll
        for (int k = 0; k < 16; k++) {
            f4 av = *(const f4*)&As[k][ty*4];
            f4 bv = *(const f4*)&Bs[k][tx*4];
            float a[4] = {av.x, av.y, av.z, av.w};
            float bb[4] = {bv.x, bv.y, bv.z, bv.w};
            #pragma unroll
            for (int i = 0; i < 4; i++)
                #pragma unroll
                for (int j = 0; j < 4; j++)
                    acc[i][j] += a[i]*bb[j];
        }
        __syncthreads();
    }

    #pragma unroll
    for (int i = 0; i < 4; i++) {
        int m = m0 + ty*4 + i;
        if (m >= M) continue;
        #pragma unroll
        for (int j = 0; j < 4; j++) {
            int n = n0 + tx*4 + j;
            float v = acc[i][j];
            if (BIAS_COL) v += bias[n];
            if (BIAS_ROW) v += bias[m];
            if (GELU)     v = gelu_f(v);
            float* cp = &C[(size_t)m*ldc + n];
            if (RESID) v += *cp;
            *cp = v;
        }
    }
}

// ---------------------------------------------------------------------------
// Flash attention: one block per (b, head, 64-row Q tile). Online softmax.
// Thread (r = t>>2, c = t&3): owns Q row r, S columns kk = 4j+c (bank-spread),
// O dims c*16..c*16+15.
// ---------------------------------------------------------------------------
__global__ __launch_bounds__(256) void attn_kernel(
    const float* __restrict__ qkv,   // [B,N,3*INNER] = [q|k|v], head h at h*64
    float* __restrict__ o)           // [B,N,INNER]
{
    const int q0   = blockIdx.x * 64;
    const int head = blockIdx.y;
    const int b    = blockIdx.z;
    const int t    = threadIdx.x;
    const int r = t >> 2, c = t & 3;

    __shared__ float Qs[64][68];
    __shared__ float Ks[64][68];
    __shared__ float Vs[64][68];
    __shared__ float Ps[64][68];

    {   // load + scale Q tile (f4, coalesced)
        const int row = t >> 4, c4 = (t & 15) * 4;
        #pragma unroll
        for (int p = 0; p < 4; p++) {
            int rr = p*16 + row;
            f4 v = *(const f4*)&qkv[((size_t)(b*N_ + q0 + rr)*(3*INNER_)) + head*DH_ + c4];
            v.x *= 0.125f; v.y *= 0.125f; v.z *= 0.125f; v.w *= 0.125f;
            *(f4*)&Qs[rr][c4] = v;
        }
    }

    float m = -INFINITY, l = 0.f;
    f4 acc[4];
    #pragma unroll
    for (int q = 0; q < 4; q++) acc[q] = make_float4(0.f, 0.f, 0.f, 0.f);

    for (int kt = 0; kt < N_/64; ++kt) {
        {   // load K,V tiles
            const int row = t >> 4, c4 = (t & 15) * 4;
            #pragma unroll
            for (int p = 0; p < 4; p++) {
                int rr = p*16 + row;
                size_t base = ((size_t)(b*N_ + kt*64 + rr)*(3*INNER_)) + head*DH_ + c4;
                *(f4*)&Ks[rr][c4] = *(const f4*)&qkv[base + INNER_];
                *(f4*)&Vs[rr][c4] = *(const f4*)&qkv[base + 2*INNER_];
            }
        }
        __syncthreads();

        float s[16];
        #pragma unroll
        for (int j = 0; j < 16; j++) s[j] = 0.f;
        #pragma unroll
        for (int d4 = 0; d4 < 16; ++d4) {
            f4 qv = *(const f4*)&Qs[r][d4*4];
            #pragma unroll
            for (int j = 0; j < 16; j++) {
                f4 kv = *(const f4*)&Ks[4*j + c][d4*4];
                s[j] += qv.x*kv.x + qv.y*kv.y + qv.z*kv.z + qv.w*kv.w;
            }
        }
        float tmax = s[0];
        #pragma unroll
        for (int j = 1; j < 16; j++) tmax = fmaxf(tmax, s[j]);
        tmax = fmaxf(tmax, __shfl_xor(tmax, 1, 64));
        tmax = fmaxf(tmax, __shfl_xor(tmax, 2, 64));
        float mnew  = fmaxf(m, tmax);
        float scalef = __expf(m - mnew);      // m = -inf first tile -> 0
        float rsum = 0.f;
        #pragma unroll
        for (int j = 0; j < 16; j++) {
            float pv = __expf(s[j] - mnew);
            rsum += pv;
            Ps[r][4*j + c] = pv;
        }
        rsum += __shfl_xor(rsum, 1, 64);
        rsum += __shfl_xor(rsum, 2, 64);
        l = l*scalef + rsum;
        #pragma unroll
        for (int q = 0; q < 4; q++) {
            acc[q].x *= scalef; acc[q].y *= scalef;
            acc[q].z *= scalef; acc[q].w *= scalef;
        }
        __syncthreads();   // Ps visible

        #pragma unroll 8
        for (int kk = 0; kk < 64; kk++) {
            float pv = Ps[r][kk];
            const f4* vr = (const f4*)&Vs[kk][c*16];
            #pragma unroll
            for (int q = 0; q < 4; q++) {
                f4 vv = vr[q];
                acc[q].x += pv*vv.x; acc[q].y += pv*vv.y;
                acc[q].z += pv*vv.z; acc[q].w += pv*vv.w;
            }
        }
        m = mnew;
        __syncthreads();   // done with Ks/Vs/Ps before next load
    }

    float inv = 1.0f / l;
    float* orow = o + ((size_t)(b*N_ + q0 + r)*INNER_) + head*DH_ + c*16;
    #pragma unroll
    for (int q = 0; q < 4; q++) {
        f4 v = acc[q];
        v.x *= inv; v.y *= inv; v.z *= inv; v.w *= inv;
        *(f4*)&orow[q*4] = v;
    }
}

// ---------------------------------------------------------------------------
// Fused 5-head MLP: per block 16 u-rows; hid = gelu(u @ w1[k] + b1[k]) in LDS,
// then 4 outputs per (row,k) reduced across 4-lane segments; sliced write.
// ---------------------------------------------------------------------------
__global__ __launch_bounds__(256) void heads_kernel(
    const float* __restrict__ u, const float* __restrict__ w1,
    const float* __restrict__ b1, const float* __restrict__ w2,
    const float* __restrict__ b2, float* __restrict__ outp)
{
    const int mt = blockIdx.x, b = blockIdx.y, t = threadIdx.x;
    const int m0 = mt * 16;
    __shared__ float u_lds[16][D_];
    __shared__ float hid[16][260];   // pad 260: phase-2 column reads 2-way max

    #pragma unroll
    for (int p = 0; p < 16; p++) {
        int mm = m0 + p;
        u_lds[p][t] = (mm < M_) ? u[((size_t)b*M_ + mm)*D_ + t] : 0.f;
    }
    __syncthreads();

    const int r2 = t >> 4, o2 = (t >> 2) & 3, seg = t & 3;
    constexpr int koff[5] = {0, 3, 4, 7, 11};
    constexpr int kcnt[5] = {3, 1, 3, 4, 3};

    #pragma unroll
    for (int k = 0; k < 5; k++) {
        float acc[16];
        float bk = b1[k*D_ + t];
        #pragma unroll
        for (int rr = 0; rr < 16; rr++) acc[rr] = bk;
        const float* w1k = w1 + (size_t)k*D_*D_;
        for (int d = 0; d < D_; d++) {
            float w = w1k[d*D_ + t];
            #pragma unroll
            for (int rr = 0; rr < 16; rr++) acc[rr] += u_lds[rr][d] * w;
        }
        #pragma unroll
        for (int rr = 0; rr < 16; rr++) hid[rr][t] = gelu_f(acc[rr]);
        __syncthreads();

        const float* w2k = w2 + k*D_*4;
        float part = 0.f;
        for (int e = seg*64; e < seg*64 + 64; e++)
            part += hid[r2][e] * w2k[e*4 + o2];
        part += __shfl_xor(part, 1, 64);
        part += __shfl_xor(part, 2, 64);
        if (seg == 0 && o2 < kcnt[k]) {
            int mm = m0 + r2;
            if (mm < M_)
                outp[((size_t)b*M_ + mm)*14 + koff[k] + o2] = part + b2[k*4 + o2];
        }
        __syncthreads();
    }
}

// ---------------------------------------------------------------------------
extern "C" void kernel_launch(void* const* d_in, const int* in_sizes, int n_in,
                              void* d_out, int out_size, void* d_ws, size_t ws_size,
                              hipStream_t stream)
{
    const float* x          = (const float*)d_in[0];
    const float* pre_emb_w  = (const float*)d_in[1];
    const float* pre_emb_b  = (const float*)d_in[2];
    const float* pre_conv_w = (const float*)d_in[3];
    const float* pre_conv_b = (const float*)d_in[4];
    const float* pos_emb    = (const float*)d_in[5];
    const float* pre_norm_g = (const float*)d_in[6];
    const float* pre_norm_b = (const float*)d_in[7];
    const float* ln1_g      = (const float*)d_in[8];
    const float* ln1_b      = (const float*)d_in[9];
    const float* qkv_w      = (const float*)d_in[10];
    const float* out_w      = (const float*)d_in[11];
    const float* out_b      = (const float*)d_in[12];
    const float* ln2_g      = (const float*)d_in[13];
    const float* ln2_b      = (const float*)d_in[14];
    const float* ff_w1      = (const float*)d_in[15];
    const float* ff_b1      = (const float*)d_in[16];
    const float* ff_w2      = (const float*)d_in[17];
    const float* ff_b2      = (const float*)d_in[18];
    const float* up_w       = (const float*)d_in[19];
    const float* up_b       = (const float*)d_in[20];
    const float* heads_w1   = (const float*)d_in[21];
    const float* heads_b1   = (const float*)d_in[22];
    const float* heads_w2   = (const float*)d_in[23];
    const float* heads_b2   = (const float*)d_in[24];
    float* out = (float*)d_out;

    // workspace layout (floats); big region shared by qkv / ffn-tmp / u
    float* h    = (float*)d_ws;                   //  2,097,152
    float* y    = h   + (size_t)B_*N_*D_;         //  2,097,152
    float* big  = y   + (size_t)B_*N_*D_;         // 14,110,720 (max of 12.58M qkv, 8.39M tmp, 14.11M u)
    float* obuf = big + (size_t)B_*M_*D_;         //  4,194,304
    // total = 22,499,328 floats = ~86 MiB

    embed_ln_kernel<<<dim3(N_, B_), 256, 0, stream>>>(
        x, pre_emb_w, pre_emb_b, pre_conv_w, pre_conv_b, pos_emb,
        pre_norm_g, pre_norm_b, h);

    const int rows = B_ * N_;   // 8192
    for (int i = 0; i < L_; i++) {
        ln_kernel<<<rows, 256, 0, stream>>>(h, y, ln1_g + i*D_, ln1_b + i*D_);
        sgemm_kernel<0,0,0,0><<<dim3((3*INNER_)/64, rows/64, 1), 256, 0, stream>>>(
            y, D_, 0, qkv_w + (size_t)i*D_*3*INNER_, 3*INNER_, 0,
            big, 3*INNER_, 0, nullptr, rows, 3*INNER_, D_);
        attn_kernel<<<dim3(N_/64, H_, B_), 256, 0, stream>>>(big, obuf);
        sgemm_kernel<1,0,0,1><<<dim3(D_/64, rows/64, 1), 256, 0, stream>>>(
            obuf, INNER_, 0, out_w + (size_t)i*INNER_*D_, D_, 0,
            h, D_, 0, out_b + i*D_, rows, D_, INNER_);
        ln_kernel<<<rows, 256, 0, stream>>>(h, y, ln2_g + i*D_, ln2_b + i*D_);
        sgemm_kernel<1,0,1,0><<<dim3(FF_/64, rows/64, 1), 256, 0, stream>>>(
            y, D_, 0, ff_w1 + (size_t)i*D_*FF_, FF_, 0,
            big, FF_, 0, ff_b1 + i*FF_, rows, FF_, D_);
        sgemm_kernel<1,0,0,1><<<dim3(D_/64, rows/64, 1), 256, 0, stream>>>(
            big, FF_, 0, ff_w2 + (size_t)i*FF_*D_, D_, 0,
            h, D_, 0, ff_b2 + i*D_, rows, D_, FF_);
    }

    // upsample conv (1x1): u[b] = up_w @ h[b] + up_b (row bias), batched over b
    sgemm_kernel<0,1,0,0><<<dim3(D_/64, (M_ + 63)/64, B_), 256, 0, stream>>>(
        up_w, N_, 0, h, D_, (long)N_*D_,
        big, D_, (long)M_*D_, up_b, M_, D_, N_);

    heads_kernel<<<dim3((M_ + 15)/16, B_), 256, 0, stream>>>(
        big, heads_w1, heads_b1, heads_w2, heads_b2, out);
}

// Round 2
// 5763.175 us; speedup vs baseline: 1.3053x; 1.3053x over previous
//
#include <hip/hip_runtime.h>
#include <math.h>

#define B_ 4
#define J_ 6890
#define D_ 256
#define L_ 4
#define H_ 8
#define DH_ 64
#define INNER_ 512
#define N_ 2048
#define FF_ 1024
#define M_ 13780
#define MP_ 13824   // M padded to multiple of 128

typedef float4 f4;
typedef __attribute__((ext_vector_type(8))) short s16x8;   // 8 bf16 (4 VGPRs)
typedef __attribute__((ext_vector_type(4))) float fx4;     // MFMA C/D

__device__ __forceinline__ float b2f(short s) {
    return __uint_as_float(((unsigned int)(unsigned short)s) << 16);
}
__device__ __forceinline__ short f2bf(float f) {   // RNE
    unsigned int u = __float_as_uint(f);
    unsigned int r = (u + 0x7FFFu + ((u >> 16) & 1u)) >> 16;
    return (short)r;
}
__device__ __forceinline__ float gelu_f(float v) {
    return 0.5f * v * (1.0f + erff(v * 0.70710678118654752440f));
}

// ---------------------------------------------------------------------------
// Fused token-embed + 1x1 conv (J->N) + pos-emb + pre-LN.  (fp32, unchanged)
// ---------------------------------------------------------------------------
__global__ __launch_bounds__(256) void embed_ln_kernel(
    const float* __restrict__ x, const float* __restrict__ emb_w,
    const float* __restrict__ emb_b, const float* __restrict__ conv_w,
    const float* __restrict__ conv_b, const float* __restrict__ pos_emb,
    const float* __restrict__ g, const float* __restrict__ beta,
    float* __restrict__ hout)
{
    const int n = blockIdx.x, b = blockIdx.y, t = threadIdx.x;
    const float* wrow = conv_w + (size_t)n * J_;
    const float* xb = x + (size_t)b * J_ * 3;
    float t0 = 0.f, t1 = 0.f, t2 = 0.f, s = 0.f;
    for (int j = t; j < J_; j += 256) {
        float w = wrow[j];
        s  += w;
        t0 += w * xb[3*j+0];
        t1 += w * xb[3*j+1];
        t2 += w * xb[3*j+2];
    }
    __shared__ float red[16];
    #pragma unroll
    for (int off = 32; off > 0; off >>= 1) {
        t0 += __shfl_down(t0, off, 64);
        t1 += __shfl_down(t1, off, 64);
        t2 += __shfl_down(t2, off, 64);
        s  += __shfl_down(s,  off, 64);
    }
    const int lane = t & 63, wid = t >> 6;
    if (lane == 0) { red[wid*4+0]=t0; red[wid*4+1]=t1; red[wid*4+2]=t2; red[wid*4+3]=s; }
    __syncthreads();
    t0 = red[0]+red[4]+red[8]+red[12];
    t1 = red[1]+red[5]+red[9]+red[13];
    t2 = red[2]+red[6]+red[10]+red[14];
    s  = red[3]+red[7]+red[11]+red[15];
    __syncthreads();

    float val = t0*emb_w[t] + t1*emb_w[D_+t] + t2*emb_w[2*D_+t]
              + s*emb_b[t] + conv_b[n] + pos_emb[(size_t)n*D_ + t];

    float sv = val, sq = val*val;
    #pragma unroll
    for (int off = 32; off > 0; off >>= 1) {
        sv += __shfl_down(sv, off, 64);
        sq += __shfl_down(sq, off, 64);
    }
    if (lane == 0) { red[wid*2]=sv; red[wid*2+1]=sq; }
    __syncthreads();
    sv = red[0]+red[2]+red[4]+red[6];
    sq = red[1]+red[3]+red[5]+red[7];
    float mu   = sv * (1.f/D_);
    float var  = sq * (1.f/D_) - mu*mu;
    float rstd = rsqrtf(fmaxf(var, 0.f) + 1e-5f);
    hout[((size_t)(b*N_ + n))*D_ + t] = (val - mu)*rstd*g[t] + beta[t];
}

// ---------------------------------------------------------------------------
// Row LayerNorm (rows of 256) fp32 -> bf16
// ---------------------------------------------------------------------------
__global__ __launch_bounds__(256) void ln_bf_kernel(
    const float* __restrict__ in, short* __restrict__ outp,
    const float* __restrict__ g, const float* __restrict__ beta)
{
    const int row = blockIdx.x, t = threadIdx.x;
    float v = in[(size_t)row*D_ + t];
    float sv = v, sq = v*v;
    #pragma unroll
    for (int off = 32; off > 0; off >>= 1) {
        sv += __shfl_down(sv, off, 64);
        sq += __shfl_down(sq, off, 64);
    }
    __shared__ float red[8];
    const int lane = t & 63, wid = t >> 6;
    if (lane == 0) { red[wid*2]=sv; red[wid*2+1]=sq; }
    __syncthreads();
    sv = red[0]+red[2]+red[4]+red[6];
    sq = red[1]+red[3]+red[5]+red[7];
    float mu   = sv * (1.f/D_);
    float var  = sq * (1.f/D_) - mu*mu;
    float rstd = rsqrtf(fmaxf(var, 0.f) + 1e-5f);
    outp[(size_t)row*D_ + t] = f2bf((v - mu)*rstd*g[t] + beta[t]);
}

// ---------------------------------------------------------------------------
// Tiled transpose-convert: out_bf16[C][R] = (in_f32[R][C])^T, R,C % 32 == 0
// ---------------------------------------------------------------------------
__global__ __launch_bounds__(256) void tcvt_kernel(
    const float* __restrict__ in, short* __restrict__ outp,
    int R, int C, long inZ, long outZ)
{
    in   += (size_t)blockIdx.z * inZ;
    outp += (size_t)blockIdx.z * outZ;
    __shared__ float tile[32][33];
    const int c0 = blockIdx.x * 32, r0 = blockIdx.y * 32;
    const int t = threadIdx.x;
    const int row = t >> 3, c4 = (t & 7) * 4;
    f4 v = *(const f4*)&in[(size_t)(r0 + row)*C + c0 + c4];
    tile[row][c4+0] = v.x; tile[row][c4+1] = v.y;
    tile[row][c4+2] = v.z; tile[row][c4+3] = v.w;
    __syncthreads();
    const int oc = t >> 3, r4 = (t & 7) * 4;
    short* dst = &outp[(size_t)(c0 + oc)*R + r0 + r4];
    #pragma unroll
    for (int j = 0; j < 4; j++) dst[j] = f2bf(tile[r4 + j][oc]);
}

// straight fp32 -> bf16 convert, n % 8 == 0, grid*256*8 == n exactly
__global__ __launch_bounds__(256) void cvt_kernel(
    const float* __restrict__ in, short* __restrict__ outp)
{
    const size_t i = ((size_t)blockIdx.x * 256 + threadIdx.x) * 8;
    f4 a = *(const f4*)&in[i];
    f4 b = *(const f4*)&in[i + 4];
    s16x8 s;
    s[0]=f2bf(a.x); s[1]=f2bf(a.y); s[2]=f2bf(a.z); s[3]=f2bf(a.w);
    s[4]=f2bf(b.x); s[5]=f2bf(b.y); s[6]=f2bf(b.z); s[7]=f2bf(b.w);
    *(s16x8*)&outp[i] = s;
}

// ---------------------------------------------------------------------------
// bf16 MFMA GEMM: C[M,N] = A[M,K] @ B[K,N], Bt given TRANSPOSED [N][K].
// 128x128 tile, BK=32, 4 waves (2x2), per wave 4x4 frags of 16x16x32.
// A rows must be readable up to ceil(M/128)*128 (callers pad buffers).
// N must be % 128. Epilogues: col-bias/row-bias/GELU/residual/bf16-out.
// ---------------------------------------------------------------------------
template<int BIAS_COL, int BIAS_ROW, int GELU, int RESID, int OUT_BF16>
__global__ __launch_bounds__(256) void gemm_bf16_kernel(
    const short* __restrict__ A, int lda, long sA,
    const short* __restrict__ Bt, int ldb, long sB,
    void* __restrict__ Cv, int ldc, long sC,
    const float* __restrict__ bias, long sBias,
    int M, int K)
{
    const int z = blockIdx.z;
    A  += (size_t)z * sA;
    Bt += (size_t)z * sB;
    const int m0 = blockIdx.y * 128, n0 = blockIdx.x * 128;
    const int t = threadIdx.x;
    const int lane = t & 63, w = t >> 6;
    const int wm = w >> 1, wn = w & 1;

    __shared__ short As[128*32];
    __shared__ short Bs[128*32];

    fx4 acc[4][4];
    #pragma unroll
    for (int i = 0; i < 4; i++)
        #pragma unroll
        for (int j = 0; j < 4; j++)
            acc[i][j] = (fx4){0.f, 0.f, 0.f, 0.f};

    const int r_a = t >> 2, co_a = (t & 3) * 8;      // staging: lane-linear 16B
    const int fr = lane & 15, fg = (lane >> 4) * 8;  // fragment row/col + k-group

    for (int k0 = 0; k0 < K; k0 += 32) {
        s16x8 va0 = *(const s16x8*)&A [(size_t)(m0 + r_a)      * lda + k0 + co_a];
        s16x8 va1 = *(const s16x8*)&A [(size_t)(m0 + 64 + r_a) * lda + k0 + co_a];
        s16x8 vb0 = *(const s16x8*)&Bt[(size_t)(n0 + r_a)      * ldb + k0 + co_a];
        s16x8 vb1 = *(const s16x8*)&Bt[(size_t)(n0 + 64 + r_a) * ldb + k0 + co_a];
        __syncthreads();                       // LDS free of prev-iter readers
        *(s16x8*)&As[r_a*32 + co_a]          = va0;
        *(s16x8*)&As[(64 + r_a)*32 + co_a]   = va1;
        *(s16x8*)&Bs[r_a*32 + co_a]          = vb0;
        *(s16x8*)&Bs[(64 + r_a)*32 + co_a]   = vb1;
        __syncthreads();

        s16x8 af[4], bfr[4];
        #pragma unroll
        for (int i = 0; i < 4; i++) {
            af[i]  = *(const s16x8*)&As[(wm*64 + i*16 + fr)*32 + fg];
            bfr[i] = *(const s16x8*)&Bs[(wn*64 + i*16 + fr)*32 + fg];
        }
        #pragma unroll
        for (int i = 0; i < 4; i++)
            #pragma unroll
            for (int j = 0; j < 4; j++)
                acc[i][j] = __builtin_amdgcn_mfma_f32_16x16x32_bf16(
                                af[i], bfr[j], acc[i][j], 0, 0, 0);
    }

    // C/D layout (m89-verified): col = lane&15, row = (lane>>4)*4 + reg
    const int cr = (lane >> 4) * 4, cc = lane & 15;
    #pragma unroll
    for (int i = 0; i < 4; i++) {
        #pragma unroll
        for (int j = 0; j < 4; j++) {
            const int gcol = n0 + wn*64 + j*16 + cc;
            #pragma unroll
            for (int r = 0; r < 4; r++) {
                const int grow = m0 + wm*64 + i*16 + cr + r;
                if (grow >= M) continue;
                float v = acc[i][j][r];
                if (BIAS_COL) v += bias[(size_t)z*sBias + gcol];
                if (BIAS_ROW) v += bias[(size_t)z*sBias + grow];
                if (GELU)     v = gelu_f(v);
                if (OUT_BF16) {
                    short* C = (short*)Cv + (size_t)z*sC;
                    C[(size_t)grow*ldc + gcol] = f2bf(v);
                } else {
                    float* C = (float*)Cv + (size_t)z*sC;
                    float* cp = &C[(size_t)grow*ldc + gcol];
                    float o = v;
                    if (RESID) o += *cp;
                    *cp = o;
                }
            }
        }
    }
}

// ---------------------------------------------------------------------------
// Flash attention (fp32 compute, bf16 I/O): block per (b, head, 64-row Q tile)
// ---------------------------------------------------------------------------
__global__ __launch_bounds__(256) void attn_kernel(
    const short* __restrict__ qkv,   // [B,N,3*INNER] bf16, [q|k|v], head at h*64
    short* __restrict__ o)           // [B,N,INNER] bf16
{
    const int q0   = blockIdx.x * 64;
    const int head = blockIdx.y;
    const int b    = blockIdx.z;
    const int t    = threadIdx.x;
    const int r = t >> 2, c = t & 3;

    __shared__ float Qs[64][68];
    __shared__ float Ks[64][68];
    __shared__ float Vs[64][68];
    __shared__ float Ps[64][68];

    const int rr8 = t >> 3, ch8 = (t & 7) * 8;
    #pragma unroll
    for (int p = 0; p < 2; p++) {
        int rr = p*32 + rr8;
        s16x8 v = *(const s16x8*)&qkv[((size_t)(b*N_ + q0 + rr)*(3*INNER_)) + head*DH_ + ch8];
        #pragma unroll
        for (int j = 0; j < 8; j++) Qs[rr][ch8 + j] = b2f(v[j]) * 0.125f;
    }

    float m = -INFINITY, l = 0.f;
    f4 acc[4];
    #pragma unroll
    for (int q = 0; q < 4; q++) acc[q] = make_float4(0.f, 0.f, 0.f, 0.f);

    for (int kt = 0; kt < N_/64; ++kt) {
        #pragma unroll
        for (int p = 0; p < 2; p++) {
            int rr = p*32 + rr8;
            size_t base = ((size_t)(b*N_ + kt*64 + rr)*(3*INNER_)) + head*DH_ + ch8;
            s16x8 kv = *(const s16x8*)&qkv[base + INNER_];
            s16x8 vv = *(const s16x8*)&qkv[base + 2*INNER_];
            #pragma unroll
            for (int j = 0; j < 8; j++) {
                Ks[rr][ch8 + j] = b2f(kv[j]);
                Vs[rr][ch8 + j] = b2f(vv[j]);
            }
        }
        __syncthreads();

        float s[16];
        #pragma unroll
        for (int j = 0; j < 16; j++) s[j] = 0.f;
        #pragma unroll
        for (int d4 = 0; d4 < 16; ++d4) {
            f4 qv = *(const f4*)&Qs[r][d4*4];
            #pragma unroll
            for (int j = 0; j < 16; j++) {
                f4 kv = *(const f4*)&Ks[4*j + c][d4*4];
                s[j] += qv.x*kv.x + qv.y*kv.y + qv.z*kv.z + qv.w*kv.w;
            }
        }
        float tmax = s[0];
        #pragma unroll
        for (int j = 1; j < 16; j++) tmax = fmaxf(tmax, s[j]);
        tmax = fmaxf(tmax, __shfl_xor(tmax, 1, 64));
        tmax = fmaxf(tmax, __shfl_xor(tmax, 2, 64));
        float mnew  = fmaxf(m, tmax);
        float scalef = __expf(m - mnew);
        float rsum = 0.f;
        #pragma unroll
        for (int j = 0; j < 16; j++) {
            float pv = __expf(s[j] - mnew);
            rsum += pv;
            Ps[r][4*j + c] = pv;
        }
        rsum += __shfl_xor(rsum, 1, 64);
        rsum += __shfl_xor(rsum, 2, 64);
        l = l*scalef + rsum;
        #pragma unroll
        for (int q = 0; q < 4; q++) {
            acc[q].x *= scalef; acc[q].y *= scalef;
            acc[q].z *= scalef; acc[q].w *= scalef;
        }
        __syncthreads();

        #pragma unroll 8
        for (int kk = 0; kk < 64; kk++) {
            float pv = Ps[r][kk];
            const f4* vr = (const f4*)&Vs[kk][c*16];
            #pragma unroll
            for (int q = 0; q < 4; q++) {
                f4 vv = vr[q];
                acc[q].x += pv*vv.x; acc[q].y += pv*vv.y;
                acc[q].z += pv*vv.z; acc[q].w += pv*vv.w;
            }
        }
        m = mnew;
        __syncthreads();
    }

    float inv = 1.0f / l;
    short* orow = o + ((size_t)(b*N_ + q0 + r)*INNER_) + head*DH_ + c*16;
    #pragma unroll
    for (int q = 0; q < 4; q++) {
        orow[q*4+0] = f2bf(acc[q].x*inv);
        orow[q*4+1] = f2bf(acc[q].y*inv);
        orow[q*4+2] = f2bf(acc[q].z*inv);
        orow[q*4+3] = f2bf(acc[q].w*inv);
    }
}

// ---------------------------------------------------------------------------
// Heads phase 2 (per head k): out[b,m,koff+o] = hid[b,m,:] @ w2[:,o] + b2[o]
// 64 rows/block, 4 threads per row (64-element K segments), shuffle-reduce.
// ---------------------------------------------------------------------------
__global__ __launch_bounds__(256) void heads2_kernel(
    const short* __restrict__ hid, const float* __restrict__ w2k,
    const float* __restrict__ b2k, float* __restrict__ outp,
    int koff, int kcnt)
{
    const int t = threadIdx.x, z = blockIdx.y;
    __shared__ float w2s[1024];
    *(f4*)&w2s[t*4] = *(const f4*)&w2k[t*4];
    __syncthreads();

    const int m = blockIdx.x*64 + (t >> 2);
    const int q = t & 3;
    float a0 = 0.f, a1 = 0.f, a2 = 0.f, a3 = 0.f;
    if (m < M_) {
        const s16x8* hp = (const s16x8*)(hid + ((size_t)z*MP_ + m)*D_ + q*64);
        #pragma unroll
        for (int c8 = 0; c8 < 8; c8++) {
            s16x8 v = hp[c8];
            #pragma unroll
            for (int j = 0; j < 8; j++) {
                float f = b2f(v[j]);
                const float* wv = &w2s[(q*64 + c8*8 + j)*4];
                a0 += f*wv[0]; a1 += f*wv[1]; a2 += f*wv[2]; a3 += f*wv[3];
            }
        }
    }
    a0 += __shfl_xor(a0, 1, 64); a0 += __shfl_xor(a0, 2, 64);
    a1 += __shfl_xor(a1, 1, 64); a1 += __shfl_xor(a1, 2, 64);
    a2 += __shfl_xor(a2, 1, 64); a2 += __shfl_xor(a2, 2, 64);
    a3 += __shfl_xor(a3, 1, 64); a3 += __shfl_xor(a3, 2, 64);
    if (q == 0 && m < M_) {
        float av[4] = {a0, a1, a2, a3};
        for (int o2 = 0; o2 < kcnt; o2++)
            outp[((size_t)z*M_ + m)*14 + koff + o2] = av[o2] + b2k[o2];
    }
}

// ---------------------------------------------------------------------------
extern "C" void kernel_launch(void* const* d_in, const int* in_sizes, int n_in,
                              void* d_out, int out_size, void* d_ws, size_t ws_size,
                              hipStream_t stream)
{
    const float* x          = (const float*)d_in[0];
    const float* pre_emb_w  = (const float*)d_in[1];
    const float* pre_emb_b  = (const float*)d_in[2];
    const float* pre_conv_w = (const float*)d_in[3];
    const float* pre_conv_b = (const float*)d_in[4];
    const float* pos_emb    = (const float*)d_in[5];
    const float* pre_norm_g = (const float*)d_in[6];
    const float* pre_norm_b = (const float*)d_in[7];
    const float* ln1_g      = (const float*)d_in[8];
    const float* ln1_b      = (const float*)d_in[9];
    const float* qkv_w      = (const float*)d_in[10];
    const float* out_w      = (const float*)d_in[11];
    const float* out_b      = (const float*)d_in[12];
    const float* ln2_g      = (const float*)d_in[13];
    const float* ln2_b      = (const float*)d_in[14];
    const float* ff_w1      = (const float*)d_in[15];
    const float* ff_b1      = (const float*)d_in[16];
    const float* ff_w2      = (const float*)d_in[17];
    const float* ff_b2      = (const float*)d_in[18];
    const float* up_w       = (const float*)d_in[19];
    const float* up_b       = (const float*)d_in[20];
    const float* heads_w1   = (const float*)d_in[21];
    const float* heads_b1   = (const float*)d_in[22];
    const float* heads_w2   = (const float*)d_in[23];
    const float* heads_b2   = (const float*)d_in[24];
    float* out = (float*)d_out;

    // ---- workspace layout (bytes), total ~121 MiB -------------------------
    char* ws = (char*)d_ws;
    float* h      = (float*)(ws);                 // 8,388,608  (fp32 residual)
    char*  R2     = ws + 8388608;                 // 56,623,104 layer scratch, reused for upw
    short* y_bf   = (short*)(R2);                 //  4,194,304
    short* qkv_bf = (short*)(R2 + 4194304);       // 25,165,824
    short* ffmid  = qkv_bf;                       // alias (disjoint lifetime)
    short* obuf   = (short*)(R2 + 29360128);      //  8,388,608
    short* qkvT   = (short*)(R2 + 37748736);      //  3,145,728
    short* outT   = (short*)(R2 + 40894464);      //  1,048,576
    short* ff1T   = (short*)(R2 + 41943040);      //  2,097,152
    short* ff2T   = (short*)(R2 + 44040192);      //  2,097,152
    short* upw_bf = (short*)(R2);                 // aliases all of R2 post-layers
    short* hT     = (short*)(ws + 65011712);      //  4,194,304
    short* u_bf   = (short*)(ws + 69206016);      // 28,311,552
    short* w1T    = (short*)(ws + 97517568);      //    655,360
    short* hid    = (short*)(ws + 98172928);      // 28,311,552

    // ---- weight transpose-converts (fp32 [K][N] -> bf16 [N][K]) -----------
    tcvt_kernel<<<dim3(1536/32,  256/32, 4), 256, 0, stream>>>(qkv_w,    qkvT, 256, 1536, 256L*1536, 1536L*256);
    tcvt_kernel<<<dim3( 256/32,  512/32, 4), 256, 0, stream>>>(out_w,    outT, 512,  256, 512L*256,  256L*512);
    tcvt_kernel<<<dim3(1024/32,  256/32, 4), 256, 0, stream>>>(ff_w1,    ff1T, 256, 1024, 256L*1024, 1024L*256);
    tcvt_kernel<<<dim3( 256/32, 1024/32, 4), 256, 0, stream>>>(ff_w2,    ff2T, 1024, 256, 1024L*256, 256L*1024);
    tcvt_kernel<<<dim3( 256/32,  256/32, 5), 256, 0, stream>>>(heads_w1, w1T,  256,  256, 256L*256,  256L*256);

    embed_ln_kernel<<<dim3(N_, B_), 256, 0, stream>>>(
        x, pre_emb_w, pre_emb_b, pre_conv_w, pre_conv_b, pos_emb,
        pre_norm_g, pre_norm_b, h);

    const int rows = B_ * N_;   // 8192
    for (int i = 0; i < L_; i++) {
        ln_bf_kernel<<<rows, 256, 0, stream>>>(h, y_bf, ln1_g + i*D_, ln1_b + i*D_);
        gemm_bf16_kernel<0,0,0,0,1><<<dim3(12, rows/128, 1), 256, 0, stream>>>(
            y_bf, 256, 0, qkvT + (size_t)i*1536*256, 256, 0,
            qkv_bf, 1536, 0, nullptr, 0, rows, 256);
        attn_kernel<<<dim3(N_/64, H_, B_), 256, 0, stream>>>(qkv_bf, obuf);
        gemm_bf16_kernel<1,0,0,1,0><<<dim3(2, rows/128, 1), 256, 0, stream>>>(
            obuf, 512, 0, outT + (size_t)i*256*512, 512, 0,
            h, 256, 0, out_b + i*D_, 0, rows, 512);
        ln_bf_kernel<<<rows, 256, 0, stream>>>(h, y_bf, ln2_g + i*D_, ln2_b + i*D_);
        gemm_bf16_kernel<1,0,1,0,1><<<dim3(8, rows/128, 1), 256, 0, stream>>>(
            y_bf, 256, 0, ff1T + (size_t)i*1024*256, 256, 0,
            ffmid, 1024, 0, ff_b1 + i*FF_, 0, rows, 256);
        gemm_bf16_kernel<1,0,0,1,0><<<dim3(2, rows/128, 1), 256, 0, stream>>>(
            ffmid, 1024, 0, ff2T + (size_t)i*256*1024, 1024, 0,
            h, 256, 0, ff_b2 + i*D_, 0, rows, 1024);
    }

    // up_w straight convert (13780*2048 = 13780 blocks * 256 thr * 8 elems)
    cvt_kernel<<<13780, 256, 0, stream>>>(up_w, upw_bf);
    // h transpose per batch: [2048,256] -> bf16 [256,2048]
    tcvt_kernel<<<dim3(256/32, 2048/32, 4), 256, 0, stream>>>(h, hT, 2048, 256, 2048L*256, 256L*2048);
    // upsample: u[b] = up_w @ h[b] + up_b (row bias)
    gemm_bf16_kernel<0,1,0,0,1><<<dim3(2, MP_/128, 4), 256, 0, stream>>>(
        upw_bf, 2048, 0, hT, 2048, 256L*2048,
        u_bf, 256, (long)MP_*256, up_b, 0, M_, 2048);

    static const int koff_h[5] = {0, 3, 4, 7, 11};
    static const int kcnt_h[5] = {3, 1, 3, 4, 3};
    for (int k = 0; k < 5; k++) {
        gemm_bf16_kernel<1,0,1,0,1><<<dim3(2, MP_/128, 4), 256, 0, stream>>>(
            u_bf, 256, (long)MP_*256, w1T + (size_t)k*256*256, 256, 0,
            hid, 256, (long)MP_*256, heads_b1 + k*256, 0, M_, 256);
        heads2_kernel<<<dim3(MP_/64, 4), 256, 0, stream>>>(
            hid, heads_w2 + (size_t)k*256*4, heads_b2 + k*4, out, koff_h[k], kcnt_h[k]);
    }
}

// Round 5
// 1601.738 us; speedup vs baseline: 4.6967x; 3.5981x over previous
//
#include <hip/hip_runtime.h>
#include <math.h>

#define B_ 4
#define J_ 6890
#define D_ 256
#define L_ 4
#define H_ 8
#define DH_ 64
#define INNER_ 512
#define N_ 2048
#define FF_ 1024
#define M_ 13780
#define MP_ 13824   // M padded to multiple of 128

typedef float4 f4;
typedef __attribute__((ext_vector_type(8))) short s16x8;   // 8 bf16 (4 VGPRs)
typedef __attribute__((ext_vector_type(4))) float fx4;     // MFMA C/D

__device__ __forceinline__ float b2f(short s) {
    return __uint_as_float(((unsigned int)(unsigned short)s) << 16);
}
__device__ __forceinline__ short f2bf(float f) {   // RNE
    unsigned int u = __float_as_uint(f);
    unsigned int r = (u + 0x7FFFu + ((u >> 16) & 1u)) >> 16;
    return (short)r;
}
__device__ __forceinline__ float gelu_f(float v) {
    return 0.5f * v * (1.0f + erff(v * 0.70710678118654752440f));
}

// ---------------------------------------------------------------------------
// Fused token-embed + 1x1 conv (J->N) + pos-emb + pre-LN.  (fp32)
// ---------------------------------------------------------------------------
__global__ __launch_bounds__(256) void embed_ln_kernel(
    const float* __restrict__ x, const float* __restrict__ emb_w,
    const float* __restrict__ emb_b, const float* __restrict__ conv_w,
    const float* __restrict__ conv_b, const float* __restrict__ pos_emb,
    const float* __restrict__ g, const float* __restrict__ beta,
    float* __restrict__ hout)
{
    const int n = blockIdx.x, b = blockIdx.y, t = threadIdx.x;
    const float* wrow = conv_w + (size_t)n * J_;
    const float* xb = x + (size_t)b * J_ * 3;
    float t0 = 0.f, t1 = 0.f, t2 = 0.f, s = 0.f;
    for (int j = t; j < J_; j += 256) {
        float w = wrow[j];
        s  += w;
        t0 += w * xb[3*j+0];
        t1 += w * xb[3*j+1];
        t2 += w * xb[3*j+2];
    }
    __shared__ float red[16];
    #pragma unroll
    for (int off = 32; off > 0; off >>= 1) {
        t0 += __shfl_down(t0, off, 64);
        t1 += __shfl_down(t1, off, 64);
        t2 += __shfl_down(t2, off, 64);
        s  += __shfl_down(s,  off, 64);
    }
    const int lane = t & 63, wid = t >> 6;
    if (lane == 0) { red[wid*4+0]=t0; red[wid*4+1]=t1; red[wid*4+2]=t2; red[wid*4+3]=s; }
    __syncthreads();
    t0 = red[0]+red[4]+red[8]+red[12];
    t1 = red[1]+red[5]+red[9]+red[13];
    t2 = red[2]+red[6]+red[10]+red[14];
    s  = red[3]+red[7]+red[11]+red[15];
    __syncthreads();

    float val = t0*emb_w[t] + t1*emb_w[D_+t] + t2*emb_w[2*D_+t]
              + s*emb_b[t] + conv_b[n] + pos_emb[(size_t)n*D_ + t];

    float sv = val, sq = val*val;
    #pragma unroll
    for (int off = 32; off > 0; off >>= 1) {
        sv += __shfl_down(sv, off, 64);
        sq += __shfl_down(sq, off, 64);
    }
    if (lane == 0) { red[wid*2]=sv; red[wid*2+1]=sq; }
    __syncthreads();
    sv = red[0]+red[2]+red[4]+red[6];
    sq = red[1]+red[3]+red[5]+red[7];
    float mu   = sv * (1.f/D_);
    float var  = sq * (1.f/D_) - mu*mu;
    float rstd = rsqrtf(fmaxf(var, 0.f) + 1e-5f);
    hout[((size_t)(b*N_ + n))*D_ + t] = (val - mu)*rstd*g[t] + beta[t];
}

// ---------------------------------------------------------------------------
// Row LayerNorm (rows of 256) fp32 -> bf16
// ---------------------------------------------------------------------------
__global__ __launch_bounds__(256) void ln_bf_kernel(
    const float* __restrict__ in, short* __restrict__ outp,
    const float* __restrict__ g, const float* __restrict__ beta)
{
    const int row = blockIdx.x, t = threadIdx.x;
    float v = in[(size_t)row*D_ + t];
    float sv = v, sq = v*v;
    #pragma unroll
    for (int off = 32; off > 0; off >>= 1) {
        sv += __shfl_down(sv, off, 64);
        sq += __shfl_down(sq, off, 64);
    }
    __shared__ float red[8];
    const int lane = t & 63, wid = t >> 6;
    if (lane == 0) { red[wid*2]=sv; red[wid*2+1]=sq; }
    __syncthreads();
    sv = red[0]+red[2]+red[4]+red[6];
    sq = red[1]+red[3]+red[5]+red[7];
    float mu   = sv * (1.f/D_);
    float var  = sq * (1.f/D_) - mu*mu;
    float rstd = rsqrtf(fmaxf(var, 0.f) + 1e-5f);
    outp[(size_t)row*D_ + t] = f2bf((v - mu)*rstd*g[t] + beta[t]);
}

// ---------------------------------------------------------------------------
// Tiled transpose-convert: out_bf16[C][R] = (in_f32[R][C])^T, R,C % 32 == 0
// ---------------------------------------------------------------------------
__global__ __launch_bounds__(256) void tcvt_kernel(
    const float* __restrict__ in, short* __restrict__ outp,
    int R, int C, long inZ, long outZ)
{
    in   += (size_t)blockIdx.z * inZ;
    outp += (size_t)blockIdx.z * outZ;
    __shared__ float tile[32][33];
    const int c0 = blockIdx.x * 32, r0 = blockIdx.y * 32;
    const int t = threadIdx.x;
    const int row = t >> 3, c4 = (t & 7) * 4;
    f4 v = *(const f4*)&in[(size_t)(r0 + row)*C + c0 + c4];
    tile[row][c4+0] = v.x; tile[row][c4+1] = v.y;
    tile[row][c4+2] = v.z; tile[row][c4+3] = v.w;
    __syncthreads();
    const int oc = t >> 3, r4 = (t & 7) * 4;
    short* dst = &outp[(size_t)(c0 + oc)*R + r0 + r4];
    #pragma unroll
    for (int j = 0; j < 4; j++) dst[j] = f2bf(tile[r4 + j][oc]);
}

// straight fp32 -> bf16 convert, grid*256*8 == n exactly
__global__ __launch_bounds__(256) void cvt_kernel(
    const float* __restrict__ in, short* __restrict__ outp)
{
    const size_t i = ((size_t)blockIdx.x * 256 + threadIdx.x) * 8;
    f4 a = *(const f4*)&in[i];
    f4 b = *(const f4*)&in[i + 4];
    s16x8 s;
    s[0]=f2bf(a.x); s[1]=f2bf(a.y); s[2]=f2bf(a.z); s[3]=f2bf(a.w);
    s[4]=f2bf(b.x); s[5]=f2bf(b.y); s[6]=f2bf(b.z); s[7]=f2bf(b.w);
    *(s16x8*)&outp[i] = s;
}

// ---------------------------------------------------------------------------
// bf16 MFMA GEMM: C[M,N] = A[M,K] @ B[K,N], Bt given TRANSPOSED [N][K].
// 128x128 tile, BK=32, 4 waves (2x2), per wave 4x4 frags of 16x16x32.
// ---------------------------------------------------------------------------
template<int BIAS_COL, int BIAS_ROW, int GELU, int RESID, int OUT_BF16>
__global__ __launch_bounds__(256) void gemm_bf16_kernel(
    const short* __restrict__ A, int lda, long sA,
    const short* __restrict__ Bt, int ldb, long sB,
    void* __restrict__ Cv, int ldc, long sC,
    const float* __restrict__ bias, long sBias,
    int M, int K)
{
    const int z = blockIdx.z;
    A  += (size_t)z * sA;
    Bt += (size_t)z * sB;
    const int m0 = blockIdx.y * 128, n0 = blockIdx.x * 128;
    const int t = threadIdx.x;
    const int lane = t & 63, w = t >> 6;
    const int wm = w >> 1, wn = w & 1;

    __shared__ short As[128*32];
    __shared__ short Bs[128*32];

    fx4 acc[4][4];
    #pragma unroll
    for (int i = 0; i < 4; i++)
        #pragma unroll
        for (int j = 0; j < 4; j++)
            acc[i][j] = (fx4){0.f, 0.f, 0.f, 0.f};

    const int r_a = t >> 2, co_a = (t & 3) * 8;
    const int fr = lane & 15, fg = (lane >> 4) * 8;

    for (int k0 = 0; k0 < K; k0 += 32) {
        s16x8 va0 = *(const s16x8*)&A [(size_t)(m0 + r_a)      * lda + k0 + co_a];
        s16x8 va1 = *(const s16x8*)&A [(size_t)(m0 + 64 + r_a) * lda + k0 + co_a];
        s16x8 vb0 = *(const s16x8*)&Bt[(size_t)(n0 + r_a)      * ldb + k0 + co_a];
        s16x8 vb1 = *(const s16x8*)&Bt[(size_t)(n0 + 64 + r_a) * ldb + k0 + co_a];
        __syncthreads();
        *(s16x8*)&As[r_a*32 + co_a]          = va0;
        *(s16x8*)&As[(64 + r_a)*32 + co_a]   = va1;
        *(s16x8*)&Bs[r_a*32 + co_a]          = vb0;
        *(s16x8*)&Bs[(64 + r_a)*32 + co_a]   = vb1;
        __syncthreads();

        s16x8 af[4], bfr[4];
        #pragma unroll
        for (int i = 0; i < 4; i++) {
            af[i]  = *(const s16x8*)&As[(wm*64 + i*16 + fr)*32 + fg];
            bfr[i] = *(const s16x8*)&Bs[(wn*64 + i*16 + fr)*32 + fg];
        }
        #pragma unroll
        for (int i = 0; i < 4; i++)
            #pragma unroll
            for (int j = 0; j < 4; j++)
                acc[i][j] = __builtin_amdgcn_mfma_f32_16x16x32_bf16(
                                af[i], bfr[j], acc[i][j], 0, 0, 0);
    }

    const int cr = (lane >> 4) * 4, cc = lane & 15;
    #pragma unroll
    for (int i = 0; i < 4; i++) {
        #pragma unroll
        for (int j = 0; j < 4; j++) {
            const int gcol = n0 + wn*64 + j*16 + cc;
            #pragma unroll
            for (int r = 0; r < 4; r++) {
                const int grow = m0 + wm*64 + i*16 + cr + r;
                if (grow >= M) continue;
                float v = acc[i][j][r];
                if (BIAS_COL) v += bias[(size_t)z*sBias + gcol];
                if (BIAS_ROW) v += bias[(size_t)z*sBias + grow];
                if (GELU)     v = gelu_f(v);
                if (OUT_BF16) {
                    short* C = (short*)Cv + (size_t)z*sC;
                    C[(size_t)grow*ldc + gcol] = f2bf(v);
                } else {
                    float* C = (float*)Cv + (size_t)z*sC;
                    float* cp = &C[(size_t)grow*ldc + gcol];
                    float o = v;
                    if (RESID) o += *cp;
                    *cp = o;
                }
            }
        }
    }
}

// ---------------------------------------------------------------------------
// MFMA flash attention. Block = 4 waves, 128 q-rows per block (32/wave),
// KV-tile 64. Swapped QK^T (S^T = K·Q^T) so softmax state is lane-local;
// PV as O^T = V^T·P^T so rescale is lane-local too. All LDS tiles pitch-64
// bf16 with XOR swizzle byte^=(row&7)<<4 (T2) for conflict-free b128 frags.
// ---------------------------------------------------------------------------
__global__ __launch_bounds__(256) void attn_mfma_kernel(
    const short* __restrict__ qkv,   // [B,N,1536] bf16, [q|k|v], head at h*64
    short* __restrict__ o)           // [B,N,512] bf16
{
    const int q0 = blockIdx.x * 128;
    const int head = blockIdx.y;
    const int b = blockIdx.z;
    const int t = threadIdx.x;
    const int lane = t & 63, wq = t >> 6;
    const int g = lane >> 4, i16 = lane & 15;

    __shared__ short Kl[64*64];    // [kv][dh]  8 KB
    __shared__ short Vtl[64*64];   // [dh][kv]  8 KB
    __shared__ short Pl[128*64];   // [q][kv] then reused as O [q][dh]  16 KB
    char* const Kb = (char*)Kl;
    char* const Vb = (char*)Vtl;
    char* const Pb = (char*)Pl;

    // Q held in registers: B-fragment layout = row-major read of own q rows
    s16x8 qreg[2][2];
    #pragma unroll
    for (int qf = 0; qf < 2; qf++) {
        const int qg = q0 + wq*32 + i16 + 16*qf;
        const short* qp = qkv + (size_t)(b*N_ + qg)*1536 + head*DH_;
        #pragma unroll
        for (int ks = 0; ks < 2; ks++)
            qreg[qf][ks] = *(const s16x8*)&qp[8*g + 32*ks];
    }

    fx4 oacc[4][2];
    #pragma unroll
    for (int df = 0; df < 4; df++)
        #pragma unroll
        for (int qf = 0; qf < 2; qf++)
            oacc[df][qf] = (fx4){0.f, 0.f, 0.f, 0.f};
    float mst[2] = {-INFINITY, -INFINITY};
    float lst[2] = {0.f, 0.f};

    const int sr = t >> 2, scol = (t & 3) * 16;    // staging: row, col16
    const int swr = (sr & 7) << 4;
    const int qrow0 = wq*32 + i16, qrow1 = qrow0 + 16;
    const int swq0 = (qrow0 & 7) << 4, swq1 = (qrow1 & 7) << 4;

    for (int kt = 0; kt < N_/64; ++kt) {
        // global loads first (no LDS dependency) so they overlap the barrier
        const short* kp = qkv + (size_t)(b*N_ + kt*64 + sr)*1536 + INNER_ + head*DH_ + scol;
        s16x8 k0 = *(const s16x8*)kp;
        s16x8 k1 = *(const s16x8*)(kp + 8);
        s16x8 v0 = *(const s16x8*)(kp + INNER_);
        s16x8 v1 = *(const s16x8*)(kp + INNER_ + 8);
        __syncthreads();                       // prev tile's readers done
        *(s16x8*)(Kb + sr*128 + ((2*scol)      ^ swr)) = k0;
        *(s16x8*)(Kb + sr*128 + ((2*scol + 16) ^ swr)) = k1;
        #pragma unroll
        for (int j = 0; j < 8; j++) {          // V transposed scatter
            *(short*)(Vb + (scol+j)*128   + ((2*sr) ^ (j<<4))) = v0[j];
            *(short*)(Vb + (scol+8+j)*128 + ((2*sr) ^ (j<<4))) = v1[j];
        }
        __syncthreads();

        // ---- S^T = K · Q^T ------------------------------------------------
        fx4 sacc[4][2];
        #pragma unroll
        for (int kvf = 0; kvf < 4; kvf++)
            #pragma unroll
            for (int qf = 0; qf < 2; qf++)
                sacc[kvf][qf] = (fx4){0.f, 0.f, 0.f, 0.f};
        #pragma unroll
        for (int ks = 0; ks < 2; ks++) {
            #pragma unroll
            for (int kvf = 0; kvf < 4; kvf++) {
                const int kv = i16 + 16*kvf;
                s16x8 ka = *(const s16x8*)(Kb + kv*128 + ((16*g + 64*ks) ^ ((kv&7)<<4)));
                #pragma unroll
                for (int qf = 0; qf < 2; qf++)
                    sacc[kvf][qf] = __builtin_amdgcn_mfma_f32_16x16x32_bf16(
                                        ka, qreg[qf][ks], sacc[kvf][qf], 0, 0, 0);
            }
        }

        // ---- online softmax (all state lane-local, q = lane&15+16qf) ------
        #pragma unroll
        for (int qf = 0; qf < 2; qf++) {
            float sv[16];
            #pragma unroll
            for (int kvf = 0; kvf < 4; kvf++)
                #pragma unroll
                for (int r = 0; r < 4; r++)
                    sv[kvf*4+r] = sacc[kvf][qf][r] * 0.125f;
            float tm = sv[0];
            #pragma unroll
            for (int k = 1; k < 16; k++) tm = fmaxf(tm, sv[k]);
            tm = fmaxf(tm, __shfl_xor(tm, 16, 64));
            tm = fmaxf(tm, __shfl_xor(tm, 32, 64));
            const float mn  = fmaxf(qf ? mst[1] : mst[0], tm);
            const float scl = __expf((qf ? mst[1] : mst[0]) - mn);
            float rs = 0.f;
            float p[16];
            #pragma unroll
            for (int k = 0; k < 16; k++) { p[k] = __expf(sv[k] - mn); rs += p[k]; }
            rs += __shfl_xor(rs, 16, 64);
            rs += __shfl_xor(rs, 32, 64);
            if (qf) { lst[1] = lst[1]*scl + rs; mst[1] = mn; }
            else    { lst[0] = lst[0]*scl + rs; mst[0] = mn; }
            #pragma unroll
            for (int df = 0; df < 4; df++) {
                oacc[df][qf][0] *= scl; oacc[df][qf][1] *= scl;
                oacc[df][qf][2] *= scl; oacc[df][qf][3] *= scl;
            }
            const int qr = qf ? qrow1 : qrow0;
            const int sq = qf ? swq1 : swq0;
            #pragma unroll
            for (int kvf = 0; kvf < 4; kvf++) {
                uint2 wv;
                wv.x = (unsigned int)(unsigned short)f2bf(p[4*kvf+0]) |
                       ((unsigned int)(unsigned short)f2bf(p[4*kvf+1]) << 16);
                wv.y = (unsigned int)(unsigned short)f2bf(p[4*kvf+2]) |
                       ((unsigned int)(unsigned short)f2bf(p[4*kvf+3]) << 16);
                *(uint2*)(Pb + qr*128 + ((8*g + 32*kvf) ^ sq)) = wv;
            }
        }

        // wave-local P handoff: writes above are re-read below by other lanes
        // of the SAME wave (no __syncthreads). Force drain + no reordering.
        asm volatile("s_waitcnt lgkmcnt(0)" ::: "memory");
        __builtin_amdgcn_sched_barrier(0);

        // ---- O^T += V^T · P^T ---------------------------------------------
        #pragma unroll
        for (int ks = 0; ks < 2; ks++) {
            s16x8 pf0 = *(const s16x8*)(Pb + qrow0*128 + ((16*g + 64*ks) ^ swq0));
            s16x8 pf1 = *(const s16x8*)(Pb + qrow1*128 + ((16*g + 64*ks) ^ swq1));
            #pragma unroll
            for (int df = 0; df < 4; df++) {
                const int dh = i16 + 16*df;
                s16x8 va = *(const s16x8*)(Vb + dh*128 + ((16*g + 64*ks) ^ ((dh&7)<<4)));
                oacc[df][0] = __builtin_amdgcn_mfma_f32_16x16x32_bf16(va, pf0, oacc[df][0], 0, 0, 0);
                oacc[df][1] = __builtin_amdgcn_mfma_f32_16x16x32_bf16(va, pf1, oacc[df][1], 0, 0, 0);
            }
        }
    }

    // ---- epilogue: normalize, stage O in Pl, coalesced global write -------
    const float inv0 = 1.f / lst[0], inv1 = 1.f / lst[1];
    #pragma unroll
    for (int df = 0; df < 4; df++)
        #pragma unroll
        for (int r = 0; r < 4; r++) {
            const int dh = 4*g + r + 16*df;
            *(short*)(Pb + qrow0*128 + ((2*dh) ^ swq0)) = f2bf(oacc[df][0][r]*inv0);
            *(short*)(Pb + qrow1*128 + ((2*dh) ^ swq1)) = f2bf(oacc[df][1][r]*inv1);
        }
    __syncthreads();
    {
        const int qr = t >> 1, h2 = t & 1;
        const int sq = (qr & 7) << 4;
        short* op = o + (size_t)(b*N_ + q0 + qr)*INNER_ + head*DH_ + 32*h2;
        #pragma unroll
        for (int e = 0; e < 4; e++) {
            s16x8 vv = *(const s16x8*)(Pb + qr*128 + ((64*h2 + 16*e) ^ sq));
            *(s16x8*)&op[8*e] = vv;
        }
    }
}

// ---------------------------------------------------------------------------
// Heads phase 2 (per head k): out[b,m,koff+o] = hid[b,m,:] @ w2[:,o] + b2[o]
// ---------------------------------------------------------------------------
__global__ __launch_bounds__(256) void heads2_kernel(
    const short* __restrict__ hid, const float* __restrict__ w2k,
    const float* __restrict__ b2k, float* __restrict__ outp,
    int koff, int kcnt)
{
    const int t = threadIdx.x, z = blockIdx.y;
    __shared__ float w2s[1024];
    *(f4*)&w2s[t*4] = *(const f4*)&w2k[t*4];
    __syncthreads();

    const int m = blockIdx.x*64 + (t >> 2);
    const int q = t & 3;
    float a0 = 0.f, a1 = 0.f, a2 = 0.f, a3 = 0.f;
    if (m < M_) {
        const s16x8* hp = (const s16x8*)(hid + ((size_t)z*MP_ + m)*D_ + q*64);
        #pragma unroll
        for (int c8 = 0; c8 < 8; c8++) {
            s16x8 v = hp[c8];
            #pragma unroll
            for (int j = 0; j < 8; j++) {
                float f = b2f(v[j]);
                const float* wv = &w2s[(q*64 + c8*8 + j)*4];
                a0 += f*wv[0]; a1 += f*wv[1]; a2 += f*wv[2]; a3 += f*wv[3];
            }
        }
    }
    a0 += __shfl_xor(a0, 1, 64); a0 += __shfl_xor(a0, 2, 64);
    a1 += __shfl_xor(a1, 1, 64); a1 += __shfl_xor(a1, 2, 64);
    a2 += __shfl_xor(a2, 1, 64); a2 += __shfl_xor(a2, 2, 64);
    a3 += __shfl_xor(a3, 1, 64); a3 += __shfl_xor(a3, 2, 64);
    if (q == 0 && m < M_) {
        float av[4] = {a0, a1, a2, a3};
        for (int o2 = 0; o2 < kcnt; o2++)
            outp[((size_t)z*M_ + m)*14 + koff + o2] = av[o2] + b2k[o2];
    }
}

// ---------------------------------------------------------------------------
extern "C" void kernel_launch(void* const* d_in, const int* in_sizes, int n_in,
                              void* d_out, int out_size, void* d_ws, size_t ws_size,
                              hipStream_t stream)
{
    const float* x          = (const float*)d_in[0];
    const float* pre_emb_w  = (const float*)d_in[1];
    const float* pre_emb_b  = (const float*)d_in[2];
    const float* pre_conv_w = (const float*)d_in[3];
    const float* pre_conv_b = (const float*)d_in[4];
    const float* pos_emb    = (const float*)d_in[5];
    const float* pre_norm_g = (const float*)d_in[6];
    const float* pre_norm_b = (const float*)d_in[7];
    const float* ln1_g      = (const float*)d_in[8];
    const float* ln1_b      = (const float*)d_in[9];
    const float* qkv_w      = (const float*)d_in[10];
    const float* out_w      = (const float*)d_in[11];
    const float* out_b      = (const float*)d_in[12];
    const float* ln2_g      = (const float*)d_in[13];
    const float* ln2_b      = (const float*)d_in[14];
    const float* ff_w1      = (const float*)d_in[15];
    const float* ff_b1      = (const float*)d_in[16];
    const float* ff_w2      = (const float*)d_in[17];
    const float* ff_b2      = (const float*)d_in[18];
    const float* up_w       = (const float*)d_in[19];
    const float* up_b       = (const float*)d_in[20];
    const float* heads_w1   = (const float*)d_in[21];
    const float* heads_b1   = (const float*)d_in[22];
    const float* heads_w2   = (const float*)d_in[23];
    const float* heads_b2   = (const float*)d_in[24];
    float* out = (float*)d_out;

    // ---- workspace layout (bytes), total ~121 MiB -------------------------
    char* ws = (char*)d_ws;
    float* h      = (float*)(ws);                 //  8,388,608 (fp32 residual)
    char*  R2     = ws + 8388608;
    short* y_bf   = (short*)(R2);                 //  4,194,304
    short* qkv_bf = (short*)(R2 + 4194304);       // 25,165,824
    short* ffmid  = qkv_bf;                       // alias (disjoint lifetime)
    short* obuf   = (short*)(R2 + 29360128);      //  8,388,608
    short* qkvT   = (short*)(R2 + 37748736);      //  3,145,728
    short* outT   = (short*)(R2 + 40894464);      //  1,048,576
    short* ff1T   = (short*)(R2 + 41943040);      //  2,097,152
    short* ff2T   = (short*)(R2 + 44040192);      //  2,097,152
    short* upw_bf = (short*)(R2);                 // aliases R2 post-layers
    short* hT     = (short*)(ws + 65011712);      //  4,194,304
    short* u_bf   = (short*)(ws + 69206016);      // 28,311,552
    short* w1T    = (short*)(ws + 97517568);      //    655,360
    short* hid    = (short*)(ws + 98172928);      // 28,311,552

    // ---- weight transpose-converts (fp32 [K][N] -> bf16 [N][K]) -----------
    tcvt_kernel<<<dim3(1536/32,  256/32, 4), 256, 0, stream>>>(qkv_w,    qkvT, 256, 1536, 256L*1536, 1536L*256);
    tcvt_kernel<<<dim3( 256/32,  512/32, 4), 256, 0, stream>>>(out_w,    outT, 512,  256, 512L*256,  256L*512);
    tcvt_kernel<<<dim3(1024/32,  256/32, 4), 256, 0, stream>>>(ff_w1,    ff1T, 256, 1024, 256L*1024, 1024L*256);
    tcvt_kernel<<<dim3( 256/32, 1024/32, 4), 256, 0, stream>>>(ff_w2,    ff2T, 1024, 256, 1024L*256, 256L*1024);
    tcvt_kernel<<<dim3( 256/32,  256/32, 5), 256, 0, stream>>>(heads_w1, w1T,  256,  256, 256L*256,  256L*256);

    embed_ln_kernel<<<dim3(N_, B_), 256, 0, stream>>>(
        x, pre_emb_w, pre_emb_b, pre_conv_w, pre_conv_b, pos_emb,
        pre_norm_g, pre_norm_b, h);

    const int rows = B_ * N_;   // 8192
    for (int i = 0; i < L_; i++) {
        ln_bf_kernel<<<rows, 256, 0, stream>>>(h, y_bf, ln1_g + i*D_, ln1_b + i*D_);
        gemm_bf16_kernel<0,0,0,0,1><<<dim3(12, rows/128, 1), 256, 0, stream>>>(
            y_bf, 256, 0, qkvT + (size_t)i*1536*256, 256, 0,
            qkv_bf, 1536, 0, nullptr, 0, rows, 256);
        attn_mfma_kernel<<<dim3(N_/128, H_, B_), 256, 0, stream>>>(qkv_bf, obuf);
        gemm_bf16_kernel<1,0,0,1,0><<<dim3(2, rows/128, 1), 256, 0, stream>>>(
            obuf, 512, 0, outT + (size_t)i*256*512, 512, 0,
            h, 256, 0, out_b + i*D_, 0, rows, 512);
        ln_bf_kernel<<<rows, 256, 0, stream>>>(h, y_bf, ln2_g + i*D_, ln2_b + i*D_);
        gemm_bf16_kernel<1,0,1,0,1><<<dim3(8, rows/128, 1), 256, 0, stream>>>(
            y_bf, 256, 0, ff1T + (size_t)i*1024*256, 256, 0,
            ffmid, 1024, 0, ff_b1 + i*FF_, 0, rows, 256);
        gemm_bf16_kernel<1,0,0,1,0><<<dim3(2, rows/128, 1), 256, 0, stream>>>(
            ffmid, 1024, 0, ff2T + (size_t)i*256*1024, 1024, 0,
            h, 256, 0, ff_b2 + i*D_, 0, rows, 1024);
    }

    // up_w straight convert
    cvt_kernel<<<13780, 256, 0, stream>>>(up_w, upw_bf);
    // h transpose per batch: [2048,256] -> bf16 [256,2048]
    tcvt_kernel<<<dim3(256/32, 2048/32, 4), 256, 0, stream>>>(h, hT, 2048, 256, 2048L*256, 256L*2048);
    // upsample: u[b] = up_w @ h[b] + up_b (row bias)
    gemm_bf16_kernel<0,1,0,0,1><<<dim3(2, MP_/128, 4), 256, 0, stream>>>(
        upw_bf, 2048, 0, hT, 2048, 256L*2048,
        u_bf, 256, (long)MP_*256, up_b, 0, M_, 2048);

    static const int koff_h[5] = {0, 3, 4, 7, 11};
    static const int kcnt_h[5] = {3, 1, 3, 4, 3};
    for (int k = 0; k < 5; k++) {
        gemm_bf16_kernel<1,0,1,0,1><<<dim3(2, MP_/128, 4), 256, 0, stream>>>(
            u_bf, 256, (long)MP_*256, w1T + (size_t)k*256*256, 256, 0,
            hid, 256, (long)MP_*256, heads_b1 + k*256, 0, M_, 256);
        heads2_kernel<<<dim3(MP_/64, 4), 256, 0, stream>>>(
            hid, heads_w2 + (size_t)k*256*4, heads_b2 + k*4, out, koff_h[k], kcnt_h[k]);
    }
}